// Round 4
// baseline (223.784 us; speedup 1.0000x reference)
//
#include <hip/hip_runtime.h>
#include <math.h>

// Problem constants (B=4, T=2048, C=576, H=12, D=48)
#define Bn 4
#define Tn 2048
#define Cn 576
#define Hn 12
#define Dn 48
#define Mn (Bn*Tn)          // 8192 rows

// log2(e) / sqrt(48) — folded into q so attention uses exp2 directly
#define QSCALE (1.4426950408889634f * 0.14433756729740643f)

typedef short  short8  __attribute__((ext_vector_type(8)));   // 8 bf16 (4 VGPRs)
typedef float  floatx4 __attribute__((ext_vector_type(4)));   // MFMA acc
typedef unsigned short ushort_t;
typedef unsigned short ushort8_t __attribute__((ext_vector_type(8))); // 16B

static __device__ __forceinline__ unsigned short f2bf(float f) {
    union { float f; unsigned int u; } v; v.f = f;
    unsigned int r = v.u + 0x7FFFu + ((v.u >> 16) & 1u);   // round-to-nearest-even
    return (unsigned short)(r >> 16);
}

// truncation-pack two fp32 -> packed bf16x2 (P >= 0, rel err <= 2^-8)
static __device__ __forceinline__ unsigned int pack_trunc(float a, float b) {
    union { float f; unsigned int u; } ua, ub; ua.f = a; ub.f = b;
    return (ua.u >> 16) | (ub.u & 0xFFFF0000u);
}

// async global->LDS, 16B per lane (attn only; GEMMs load fragments direct)
static __device__ __forceinline__ void gload16(void* lds, const void* g) {
    __builtin_amdgcn_global_load_lds(
        (const __attribute__((address_space(1))) void*)g,
        (__attribute__((address_space(3))) void*)lds, 16, 0, 0);
}

// ---------------------------------------------------------------------------
// fused fp32 -> bf16 cast of all three inputs (one launch) + zb zeroing
// ---------------------------------------------------------------------------
__global__ __launch_bounds__(256)
void cast3(const float* __restrict__ a, ushort_t* __restrict__ oa, int na4,
           const float* __restrict__ b, ushort_t* __restrict__ ob, int nb4,
           const float* __restrict__ c, ushort_t* __restrict__ oc, int nc4,
           ushort_t* __restrict__ zb)
{
    int i = blockIdx.x * 256 + threadIdx.x;
    if (blockIdx.x == 0 && threadIdx.x < 16) {
        float4 z = (float4){0.f, 0.f, 0.f, 0.f};
        ((float4*)zb)[threadIdx.x] = z;          // 256 B of zeros
    }
    const float* src; ushort_t* dst; int idx;
    if (i < na4)                  { src = a; dst = oa; idx = i; }
    else if (i < na4 + nb4)       { src = b; dst = ob; idx = i - na4; }
    else if (i < na4 + nb4 + nc4) { src = c; dst = oc; idx = i - na4 - nb4; }
    else return;
    float4 v = ((const float4*)src)[idx];
    ushort4 o;
    o.x = f2bf(v.x); o.y = f2bf(v.y); o.z = f2bf(v.z); o.w = f2bf(v.w);
    ((ushort4*)dst)[idx] = o;
}

// ---------------------------------------------------------------------------
// ROUND-12 QKV GEMM: TLP experiment.  Same barrier-free direct-load register
// GEMM as r11, but 4-wave blocks (128x128 tile, 2Mx2N waves, wave-tile 64x64)
// and 896 blocks (3.5/CU).  r0-r3 showed all 8-wave/224-864-block variants
// stuck at 49-60us with occupancy <=20% (~1 resident block/CU, nothing to
// hide 200-900cy L2/L3 latency); attn at 36% occupancy gets exactly 2x the
// pipe utilization.  Per-wave footprint ~164 unified regs -> 3 waves/SIMD ->
// 3 resident blocks = 12 waves/CU, 3x current TLP, independent VMEM streams.
// LDS only for the coalescing epilogue (34KB, whole tile at once).
// Grid: 896 = 8 XCD x (8 m-groups x 14 n); N padded 1728->1792.
// ---------------------------------------------------------------------------
__global__ __launch_bounds__(256)
void gemm_qkv(const ushort_t* __restrict__ A, const ushort_t* __restrict__ W,
              ushort_t* __restrict__ outb)
{
    __shared__ __align__(16) ushort_t Lc[128 * 136];   // 34816 B

    const int tid  = threadIdx.x;
    const int wave = tid >> 6;
    const int lane = tid & 63;
    const int m    = lane & 15;
    const int g    = lane >> 4;
    const int wr   = wave >> 1;      // m-half 0..1 (64 rows)
    const int wn   = wave & 1;       // n-half 0..1 (64 cols)

    const int bid  = blockIdx.x;
    const int xcd  = bid & 7;
    const int slot = bid >> 3;       // 0..111
    const int ng   = slot % 14;
    const int mg   = xcd + 8 * (slot / 14);   // 0..63
    const int m0   = mg * 128;
    const int n0g  = ng * 128;

    const ushort_t* Ab = A + (size_t)(m0  + wr * 64 + m) * Cn + g * 8;
    const ushort_t* Wb = W + (size_t)(n0g + wn * 64 + m) * Cn + g * 8;

    floatx4 acc[4][4];
    #pragma unroll
    for (int i = 0; i < 4; ++i)
        #pragma unroll
        for (int j = 0; j < 4; ++j)
            acc[i][j] = (floatx4){0.f, 0.f, 0.f, 0.f};

    #pragma unroll 2
    for (int h = 0; h < 18; ++h) {
        short8 af[4], bf[4];
        #pragma unroll
        for (int mf = 0; mf < 4; ++mf)
            af[mf] = *(const short8*)(Ab + (size_t)mf * 16 * Cn + h * 32);
        #pragma unroll
        for (int nf = 0; nf < 4; ++nf)
            bf[nf] = *(const short8*)(Wb + (size_t)nf * 16 * Cn + h * 32);
        #pragma unroll
        for (int mf = 0; mf < 4; ++mf)
            #pragma unroll
            for (int nf = 0; nf < 4; ++nf)
                acc[mf][nf] = __builtin_amdgcn_mfma_f32_16x16x32_bf16(
                    af[mf], bf[nf], acc[mf][nf], 0, 0, 0);
    }

    // ---- epilogue: D row(m-dim) = m0+wr*64+mf*16+g*4+r, col(n-local) =
    //      wn*64+nf*16+m.  Tile is n-uniform in kind except ng=4 (q|k mix,
    //      handled per-chunk); ng>=9 is pure v (1152 = 9*128). ----
    const size_t per = (size_t)Bn * Hn * Tn * Dn;
    const int b  = m0 >> 11;
    const int t0 = m0 & 2047;
    const bool vmode = (n0g >= 1152);

    if (!vmode) {
        // row-major Lq[128][136]
        #pragma unroll
        for (int mf = 0; mf < 4; ++mf)
            #pragma unroll
            for (int nf = 0; nf < 4; ++nf) {
                const int  nfb = n0g + wn * 64 + nf * 16;   // frag n base
                const float sc = (nfb < 576) ? QSCALE : 1.0f;
                const int col = wn * 64 + nf * 16 + m;
                const int rb  = wr * 64 + mf * 16 + g * 4;
                #pragma unroll
                for (int r = 0; r < 4; ++r)
                    Lc[(rb + r) * 136 + col] = f2bf(acc[mf][nf][r] * sc);
            }
        __syncthreads();
        // q/k: [B,H,T,48]; 16B chunks along d (8|48 -> no head straddle)
        #pragma unroll
        for (int it = 0; it < 8; ++it) {
            const int c   = tid + it * 256;
            const int row = c >> 4;
            const int c8  = (c & 15) * 8;
            const int n   = n0g + c8;
            const int which = (n >= 576);
            const int nn  = n - which * 576;
            const int h   = nn / 48, d = nn - h * 48;
            ushort_t* dst = outb + (size_t)which * per
                + ((size_t)(b * Hn + h) * Tn + t0 + row) * Dn + d;
            *(ushort8_t*)dst = *(const ushort8_t*)&Lc[row * 136 + c8];
        }
    } else {
        // transposed Lv[128 cols][136]: col-major stage for [B,H,48,T] writes
        #pragma unroll
        for (int mf = 0; mf < 4; ++mf)
            #pragma unroll
            for (int nf = 0; nf < 4; ++nf) {
                const int col = wn * 64 + nf * 16 + m;
                const int rb  = wr * 64 + mf * 16 + g * 4;
                ushort4 pk;
                pk.x = f2bf(acc[mf][nf][0]); pk.y = f2bf(acc[mf][nf][1]);
                pk.z = f2bf(acc[mf][nf][2]); pk.w = f2bf(acc[mf][nf][3]);
                *(ushort4*)&Lc[col * 136 + rb] = pk;
            }
        __syncthreads();
        // v: [B,H,48,T]; 16B chunks along t; skip pad cols (n >= 1728)
        #pragma unroll
        for (int it = 0; it < 8; ++it) {
            const int c   = tid + it * 256;
            const int col = c >> 4;
            const int rc  = (c & 15) * 8;
            const int n   = n0g + col;
            if (n < 1728) {
                const int dd = n - 1152;
                const int h  = dd / 48, d = dd - h * 48;
                ushort_t* dst = outb + 2 * per
                    + ((size_t)(b * Hn + h) * Dn + d) * Tn + t0 + rc;
                *(ushort8_t*)dst = *(const ushort8_t*)&Lc[col * 136 + rc];
            }
        }
    }
}

// ---------------------------------------------------------------------------
// ROUND-12 proj GEMM: direct-load register GEMM, 4-wave blocks stacked in M
// (tile 128x64, wave-tile 32x64), fp32 direct store, zero main-loop LDS.
// Grid 576 = 8 XCD x (8 m x 9 n).  B-panel shared by all 4 waves (L1 hits).
// ---------------------------------------------------------------------------
__global__ __launch_bounds__(256)
void gemm_proj(const ushort_t* __restrict__ A, const ushort_t* __restrict__ W,
               float* __restrict__ outf)
{
    const int tid  = threadIdx.x;
    const int wave = tid >> 6;
    const int lane = tid & 63;
    const int m    = lane & 15;
    const int g    = lane >> 4;

    const int bid  = blockIdx.x;
    const int xcd  = bid & 7;
    const int slot = bid >> 3;       // 0..71
    const int ng   = slot % 9;
    const int mg   = xcd + 8 * (slot / 9);   // 0..63
    const int m0   = mg * 128;
    const int n0   = ng * 64;

    const ushort_t* Ab = A + (size_t)(m0 + wave * 32 + m) * Cn + g * 8;
    const ushort_t* Wb = W + (size_t)(n0 + m) * Cn + g * 8;

    floatx4 acc[2][4];
    #pragma unroll
    for (int i = 0; i < 2; ++i)
        #pragma unroll
        for (int j = 0; j < 4; ++j)
            acc[i][j] = (floatx4){0.f, 0.f, 0.f, 0.f};

    #pragma unroll 2
    for (int h = 0; h < 18; ++h) {
        short8 af[2], bf[4];
        #pragma unroll
        for (int mf = 0; mf < 2; ++mf)
            af[mf] = *(const short8*)(Ab + (size_t)mf * 16 * Cn + h * 32);
        #pragma unroll
        for (int nf = 0; nf < 4; ++nf)
            bf[nf] = *(const short8*)(Wb + (size_t)nf * 16 * Cn + h * 32);
        #pragma unroll
        for (int mf = 0; mf < 2; ++mf)
            #pragma unroll
            for (int nf = 0; nf < 4; ++nf)
                acc[mf][nf] = __builtin_amdgcn_mfma_f32_16x16x32_bf16(
                    af[mf], bf[nf], acc[mf][nf], 0, 0, 0);
    }

    // direct fp32 store: 16-lane runs of 64B along n
    #pragma unroll
    for (int mf = 0; mf < 2; ++mf) {
        #pragma unroll
        for (int r = 0; r < 4; ++r) {
            const int mrow = m0 + wave * 32 + mf * 16 + g * 4 + r;
            #pragma unroll
            for (int nf = 0; nf < 4; ++nf)
                outf[(size_t)mrow * Cn + n0 + nf * 16 + m] = acc[mf][nf][r];
        }
    }
}

// ---------------------------------------------------------------------------
// Flash attention via S^T, no-max softmax, bf16 MFMA (round-7 kernel,
// round-9 interleaved-qt grid).  Unchanged: control kernel.
// ---------------------------------------------------------------------------
__global__ __launch_bounds__(512, 6)
void attn_mfma(const ushort_t* __restrict__ Q, const ushort_t* __restrict__ K,
               const ushort_t* __restrict__ V, ushort_t* __restrict__ Y,
               const ushort_t* __restrict__ zb)
{
    __shared__ __align__(16) ushort_t QPs[16][512];    // Q tile, then reused as P^T
    __shared__ __align__(16) ushort_t Ks[2][8][512];   // [buf][(ktile t, kc)]
    __shared__ __align__(16) ushort_t Vs[2][6][512];   // [buf][(dtile t, kc)]

    const int id   = blockIdx.x;
    const int kk   = id / 48;
    const int bh   = id - kk * 48;
    const int QT   = (kk & 1) ? (kk >> 1) : (15 - (kk >> 1));   // interleave big/small
    const int tid  = threadIdx.x;
    const int wave = tid >> 6;       // 0..7
    const int lane = tid & 63;
    const int m    = lane & 15;
    const int g    = lane >> 4;
    const int q0   = QT * 128;
    const int nkt  = 2 * QT + 2;     // 64-row K tiles to process

    const ushort_t* Qp = Q + (size_t)bh * Tn * Dn;
    const ushort_t* Kp = K + (size_t)bh * Tn * Dn;
    const ushort_t* Vp = V + (size_t)bh * Dn * Tn;     // [48][T]

    {
        const char* qrp = (const char*)(Qp + (size_t)(q0 + wave * 16 + m) * Dn);
        gload16(&QPs[wave * 2 + 0][0], qrp + g * 16);
        gload16(&QPs[wave * 2 + 1][0], (g < 2) ? (qrp + 64 + g * 16) : (const char*)zb);
    }

    const bool  kpad = ((wave & 1) == 1) && (g >= 2);
    const char* kptr = kpad ? (const char*)zb
        : (const char*)(Kp + (size_t)((wave >> 1) * 16 + m) * Dn) + (wave & 1) * 64 + g * 16;
    const int   kadv = kpad ? 0 : 64 * Dn * 2;         // 64 K-rows per tile
    const char* vptr = (const char*)(Vp + (size_t)((wave >> 1) * 16 + m) * Tn)
                       + (wave & 1) * 64 + g * 16;     // valid only for wave<6
    const int   vadv = 64 * 2;                         // 64 V^T-cols per tile

    gload16(&Ks[0][wave][0], kptr); kptr += kadv;
    if (wave < 6) { gload16(&Vs[0][wave][0], vptr); vptr += vadv; }
    __syncthreads();   // drains vmcnt -> Q + tile0 ready

    short8 bq[2];
    bq[0] = *(const short8*)&QPs[wave * 2 + 0][lane * 8];
    bq[1] = *(const short8*)&QPs[wave * 2 + 1][lane * 8];

    floatx4 acc[3];
    #pragma unroll
    for (int t = 0; t < 3; ++t) acc[t] = (floatx4){0.f, 0.f, 0.f, 0.f};
    float l_tot = 0.f;
    const int qrow  = q0 + wave * 16 + m;
    const int qwmin = q0 + wave * 16;
    const int qwmax = qwmin + 15;

    for (int jt = 0; jt < nkt; ++jt) {
        const int cur = jt & 1;
        const int j0  = jt * 64;
        if (jt + 1 < nkt) {
            gload16(&Ks[cur ^ 1][wave][0], kptr); kptr += kadv;
            if (wave < 6) { gload16(&Vs[cur ^ 1][wave][0], vptr); vptr += vadv; }
        }

        if (j0 <= qwmax) {
            floatx4 s[4];
            #pragma unroll
            for (int t = 0; t < 4; ++t) {
                s[t] = (floatx4){0.f, 0.f, 0.f, 0.f};
                #pragma unroll
                for (int kc = 0; kc < 2; ++kc) {
                    short8 ak = *(const short8*)&Ks[cur][t * 2 + kc][lane * 8];
                    s[t] = __builtin_amdgcn_mfma_f32_16x16x32_bf16(ak, bq[kc], s[t], 0, 0, 0);
                }
            }

            float p[4][4];
            float lsum = 0.f;
            if (j0 + 63 > qwmin) {
                #pragma unroll
                for (int t = 0; t < 4; ++t)
                    #pragma unroll
                    for (int r = 0; r < 4; ++r) {
                        int j = j0 + t * 16 + g * 4 + r;
                        float v = (j <= qrow) ? s[t][r] : -1e30f;
                        float e = __builtin_amdgcn_exp2f(v);
                        p[t][r] = e; lsum += e;
                    }
            } else {
                #pragma unroll
                for (int t = 0; t < 4; ++t)
                    #pragma unroll
                    for (int r = 0; r < 4; ++r) {
                        float e = __builtin_amdgcn_exp2f(s[t][r]);
                        p[t][r] = e; lsum += e;
                    }
            }
            lsum += __shfl_xor(lsum, 16);
            lsum += __shfl_xor(lsum, 32);
            l_tot += lsum;

            #pragma unroll
            for (int t = 0; t < 4; ++t) {
                uint2 w2;
                w2.x = pack_trunc(p[t][0], p[t][1]);
                w2.y = pack_trunc(p[t][2], p[t][3]);
                *(uint2*)&QPs[wave * 2 + (t >> 1)]
                             [(2 * (t & 1) + (g >> 1)) * 128 + m * 8 + (g & 1) * 4] = w2;
            }
            asm volatile("s_waitcnt lgkmcnt(0)" ::: "memory");

            #pragma unroll
            for (int kc = 0; kc < 2; ++kc) {
                short8 bp = *(const short8*)&QPs[wave * 2 + kc][lane * 8];
                #pragma unroll
                for (int t = 0; t < 3; ++t) {
                    short8 av = *(const short8*)&Vs[cur][t * 2 + kc][lane * 8];
                    acc[t] = __builtin_amdgcn_mfma_f32_16x16x32_bf16(av, bp, acc[t], 0, 0, 0);
                }
            }
        }

        __syncthreads();
    }

    const float inv = 1.0f / l_tot;
    const int b = bh / Hn;
    const int h = bh - b * Hn;
    ushort_t* yp = Y + ((size_t)(b * Tn + qrow)) * Cn + h * Dn;
    #pragma unroll
    for (int t = 0; t < 3; ++t) {
        ushort4 o;
        o.x = f2bf(acc[t][0] * inv);
        o.y = f2bf(acc[t][1] * inv);
        o.z = f2bf(acc[t][2] * inv);
        o.w = f2bf(acc[t][3] * inv);
        *(ushort4*)&yp[t * 16 + g * 4] = o;
    }
}

// ---------------------------------------------------------------------------
extern "C" void kernel_launch(void* const* d_in, const int* in_sizes, int n_in,
                              void* d_out, int out_size, void* d_ws, size_t ws_size,
                              hipStream_t stream)
{
    const float* x      = (const float*)d_in[0];   // [B,T,C]
    const float* w_qkv  = (const float*)d_in[1];   // [3C,C]
    const float* w_proj = (const float*)d_in[2];   // [C,C]
    float* out = (float*)d_out;                    // [B,T,C] fp32

    const size_t per = (size_t)Bn * Hn * Tn * Dn;  // 4,718,592

    ushort_t* xb  = (ushort_t*)d_ws;               // 8192*576
    ushort_t* wqb = xb  + (size_t)Mn * Cn;         // 1728*576 (+64 pad rows read into wpb)
    ushort_t* wpb = wqb + (size_t)3 * Cn * Cn;     // 576*576
    ushort_t* qkv = wpb + (size_t)Cn * Cn;         // 3*per (q | k | v^T)
    ushort_t* yb  = qkv + 3 * per;                 // 8192*576
    ushort_t* zb  = yb  + (size_t)Mn * Cn;         // 256 B of zeros (Q/K pad source)

    // fused casts (fp32 -> bf16) + zb zeroing
    const int na4 = Mn * Cn / 4, nb4 = 3 * Cn * Cn / 4, nc4 = Cn * Cn / 4;
    cast3<<<dim3((na4 + nb4 + nc4 + 255) / 256), dim3(256), 0, stream>>>(
        x, xb, na4, w_qkv, wqb, nb4, w_proj, wpb, nc4, zb);

    // QKV GEMM (M=8192, N=1792 padded): 896 x 4-wave blocks, direct-load
    gemm_qkv<<<dim3(896), dim3(256), 0, stream>>>(xb, wqb, qkv);

    // causal attention (ALiBi bias is exactly zero on the unmasked region)
    attn_mfma<<<dim3((Tn / 128) * Bn * Hn), dim3(512), 0, stream>>>(
        qkv, qkv + per, qkv + 2 * per, yb, zb);

    // output projection (M=8192, N=576) -> fp32: 576 x 4-wave blocks, direct
    gemm_proj<<<dim3(576), dim3(256), 0, stream>>>(yb, wpb, out);
}

// Round 5
// 166.891 us; speedup vs baseline: 1.3409x; 1.3409x over previous
//
#include <hip/hip_runtime.h>
#include <math.h>

// Problem constants (B=4, T=2048, C=576, H=12, D=48)
#define Bn 4
#define Tn 2048
#define Cn 576
#define Hn 12
#define Dn 48
#define Mn (Bn*Tn)          // 8192 rows

// log2(e) / sqrt(48) — folded into q so attention uses exp2 directly
#define QSCALE (1.4426950408889634f * 0.14433756729740643f)

typedef short  short8  __attribute__((ext_vector_type(8)));   // 8 bf16 (4 VGPRs)
typedef float  floatx4 __attribute__((ext_vector_type(4)));   // MFMA acc
typedef unsigned short ushort_t;
typedef unsigned short ushort8_t __attribute__((ext_vector_type(8))); // 16B

static __device__ __forceinline__ unsigned short f2bf(float f) {
    union { float f; unsigned int u; } v; v.f = f;
    unsigned int r = v.u + 0x7FFFu + ((v.u >> 16) & 1u);   // round-to-nearest-even
    return (unsigned short)(r >> 16);
}

// truncation-pack two fp32 -> packed bf16x2 (P >= 0, rel err <= 2^-8)
static __device__ __forceinline__ unsigned int pack_trunc(float a, float b) {
    union { float f; unsigned int u; } ua, ub; ua.f = a; ub.f = b;
    return (ua.u >> 16) | (ub.u & 0xFFFF0000u);
}

// async global->LDS, 16B per lane; lane l's data lands at lds + l*16 (lane-linear)
static __device__ __forceinline__ void gload16(void* lds, const void* g) {
    __builtin_amdgcn_global_load_lds(
        (const __attribute__((address_space(1))) void*)g,
        (__attribute__((address_space(3))) void*)lds, 16, 0, 0);
}

// counted vmcnt (T4): literal-dispatched
template<int N> static __device__ __forceinline__ void vmgate() {
    if constexpr (N == 0)      asm volatile("s_waitcnt vmcnt(0)" ::: "memory");
    else if constexpr (N == 4) asm volatile("s_waitcnt vmcnt(4)" ::: "memory");
    else if constexpr (N == 8) asm volatile("s_waitcnt vmcnt(8)" ::: "memory");
    // N == -1: no gate
}
static __device__ __forceinline__ void lgk0() {
    asm volatile("s_waitcnt lgkmcnt(0)" ::: "memory");
}
static __device__ __forceinline__ void barrier_fence() {
    asm volatile("" ::: "memory");
    __builtin_amdgcn_s_barrier();
    asm volatile("" ::: "memory");
}

// old-style counted waits for the MODE-1 (proj) kernel
template<int N> static __device__ __forceinline__ void wait_vm_lg() {
    if constexpr (N == 0)
        asm volatile("s_waitcnt vmcnt(0) lgkmcnt(0)" ::: "memory");
    else if constexpr (N == 3)
        asm volatile("s_waitcnt vmcnt(3) lgkmcnt(0)" ::: "memory");
    else if constexpr (N == 6)
        asm volatile("s_waitcnt vmcnt(6) lgkmcnt(0)" ::: "memory");
    else
        static_assert(N == -12345, "unsupported waitcnt immediate");
}

// ---------------------------------------------------------------------------
// fused fp32 -> bf16 cast of all three inputs (one launch) + zb zeroing
// ---------------------------------------------------------------------------
__global__ __launch_bounds__(256)
void cast3(const float* __restrict__ a, ushort_t* __restrict__ oa, int na4,
           const float* __restrict__ b, ushort_t* __restrict__ ob, int nb4,
           const float* __restrict__ c, ushort_t* __restrict__ oc, int nc4,
           ushort_t* __restrict__ zb)
{
    int i = blockIdx.x * 256 + threadIdx.x;
    if (blockIdx.x == 0 && threadIdx.x < 16) {
        float4 z = (float4){0.f, 0.f, 0.f, 0.f};
        ((float4*)zb)[threadIdx.x] = z;          // 256 B of zeros
    }
    const float* src; ushort_t* dst; int idx;
    if (i < na4)                  { src = a; dst = oa; idx = i; }
    else if (i < na4 + nb4)       { src = b; dst = ob; idx = i - na4; }
    else if (i < na4 + nb4 + nc4) { src = c; dst = oc; idx = i - na4 - nb4; }
    else return;
    float4 v = ((const float4*)src)[idx];
    ushort4 o;
    o.x = f2bf(v.x); o.y = f2bf(v.y); o.z = f2bf(v.z); o.w = f2bf(v.w);
    ((ushort4*)dst)[idx] = o;
}

// ---------------------------------------------------------------------------
// QKV GEMM: 8-phase 256x256 schedule (round-10, measured best-in-class 49.5us
// among 5 structures; this shape at K=576 plateaus ~340 TF for plain HIP).
// ---------------------------------------------------------------------------
__global__ __launch_bounds__(512)
void gemm_qkv(const ushort_t* __restrict__ A, const ushort_t* __restrict__ W,
              ushort_t* __restrict__ outb)
{
    __shared__ __align__(16) ushort_t Ls[8][8192];   // 8 x 16KB ring

    const int tid  = threadIdx.x;
    const int wave = tid >> 6;
    const int lane = tid & 63;
    const int m    = lane & 15;
    const int g    = lane >> 4;
    const int wr   = wave >> 2;      // m-half 0..1
    const int wn   = wave & 3;       // n-quarter 0..3

    const int bid  = blockIdx.x;
    const int xcd  = bid & 7;
    const int slot = bid >> 3;       // 0..27
    const int ng   = slot % 7;
    const int mg   = xcd + 8 * (slot / 7);
    const int m0   = mg * 256;
    const int n0g  = ng * 256;

    const int srow = lane >> 2;
    const int schk = (lane & 3) * 16;
    const char* aS0 = (const char*)A + (size_t)(m0  + (wave*2+0)*16 + srow) * (Cn*2) + schk;
    const char* aS1 = (const char*)A + (size_t)(m0  + (wave*2+1)*16 + srow) * (Cn*2) + schk;
    const char* bS0 = (const char*)W + (size_t)(n0g + (wave*2+0)*16 + srow) * (Cn*2) + schk;
    const char* bS1 = (const char*)W + (size_t)(n0g + (wave*2+1)*16 + srow) * (Cn*2) + schk;

    const int aoff = (wr * 128 + m) * 64 + g * 16;
    const int boff = (wn * 64  + m) * 64 + g * 16;

    floatx4 acc[8][4];
    #pragma unroll
    for (int i = 0; i < 8; ++i)
        #pragma unroll
        for (int j = 0; j < 4; ++j)
            acc[i][j] = (floatx4){0.f, 0.f, 0.f, 0.f};

    short8 af[8], bf01[2], bf23[2];

    auto stageA = [&](int s) {
        gload16(&Ls[s][(wave*2+0)*512], aS0); aS0 += 64;
        gload16(&Ls[s][(wave*2+1)*512], aS1); aS1 += 64;
    };
    auto stageB = [&](int s) {
        gload16(&Ls[s][(wave*2+0)*512], bS0); bS0 += 64;
        gload16(&Ls[s][(wave*2+1)*512], bS1); bS1 += 64;
    };
    auto loadA = [&](int s) {
        const char* base = (const char*)&Ls[s][0] + aoff;
        #pragma unroll
        for (int mf = 0; mf < 8; ++mf) af[mf] = *(const short8*)(base + mf * 1024);
    };
    auto loadB = [&](int s, int nf0, short8 (&bf)[2]) {
        const char* base = (const char*)&Ls[s][0] + boff;
        bf[0] = *(const short8*)(base + (nf0 + 0) * 1024);
        bf[1] = *(const short8*)(base + (nf0 + 1) * 1024);
    };
    auto mfma16 = [&](short8 (&bf)[2], int nf0) {
        __builtin_amdgcn_s_setprio(1);
        #pragma unroll
        for (int mf = 0; mf < 8; ++mf) {
            acc[mf][nf0]     = __builtin_amdgcn_mfma_f32_16x16x32_bf16(af[mf], bf[0], acc[mf][nf0],     0, 0, 0);
            acc[mf][nf0 + 1] = __builtin_amdgcn_mfma_f32_16x16x32_bf16(af[mf], bf[1], acc[mf][nf0 + 1], 0, 0, 0);
        }
        __builtin_amdgcn_s_setprio(0);
    };

    stageA(0); stageB(1); stageA(2); stageB(3); stageA(4); stageB(5);
    vmgate<8>();
    barrier_fence();

    #define QKV_TILE(s0, d0, d1, d2, d3, G1m, G3m) do {                         \
        constexpr int A0 = (s0) & 7,      B0 = ((s0)+1) & 7;                    \
        constexpr int A1 = ((s0)+2) & 7,  B1 = ((s0)+3) & 7;                    \
        constexpr int S0 = ((s0)+6) & 7,  S1 = ((s0)+7) & 7;                    \
        constexpr int S2 = ((s0)+8) & 7,  S3 = ((s0)+9) & 7;                    \
        loadA(A0); loadB(B0, 0, bf01);                                          \
        if (d0) stageA(S0);                                                     \
        barrier_fence(); lgk0();                                                \
        mfma16(bf01, 0);                                                        \
        barrier_fence();                                                        \
        loadB(B0, 2, bf23);                                                     \
        if (d1) stageB(S1);                                                     \
        barrier_fence(); lgk0();                                                \
        mfma16(bf23, 2);                                                        \
        vmgate<G1m>();                                                          \
        barrier_fence();                                                        \
        loadA(A1); loadB(B1, 0, bf01);                                          \
        if (d2) stageA(S2);                                                     \
        barrier_fence(); lgk0();                                                \
        mfma16(bf01, 0);                                                        \
        barrier_fence();                                                        \
        loadB(B1, 2, bf23);                                                     \
        if (d3) stageB(S3);                                                     \
        barrier_fence(); lgk0();                                                \
        mfma16(bf23, 2);                                                        \
        vmgate<G3m>();                                                          \
        barrier_fence();                                                        \
    } while (0)

    #pragma unroll 1
    for (int tt = 0; tt < 3; ++tt) {
        QKV_TILE(0, 1, 1, 1, 1, 8, 8);
        QKV_TILE(4, 1, 1, 1, 1, 8, 8);
    }
    QKV_TILE(0, 1, 1, 1, 1, 8, 8);   // t=6
    QKV_TILE(4, 1, 1, 0, 0, 8, 4);   // t=7
    QKV_TILE(0, 0, 0, 0, 0, 0, -1);  // t=8 (drain)
    #undef QKV_TILE

    const size_t per = (size_t)Bn * Hn * Tn * Dn;
    const int b  = m0 >> 11;
    const int t0 = m0 & 2047;
    ushort_t* Lc = (ushort_t*)&Ls[0][0];

    #pragma unroll
    for (int h2 = 0; h2 < 2; ++h2) {
        const int  nbase = n0g + h2 * 128;
        const bool vmode = (nbase >= 1152);    // 1152 = 9*128: half-uniform
        if ((wn >> 1) == h2) {
            if (!vmode) {
                #pragma unroll
                for (int mf = 0; mf < 8; ++mf)
                    #pragma unroll
                    for (int nf = 0; nf < 4; ++nf) {
                        const int  nfb = n0g + wn * 64 + nf * 16;
                        const float sc = (nfb < 576) ? QSCALE : 1.0f;
                        const int col = (wn & 1) * 64 + nf * 16 + m;
                        const int rb  = wr * 128 + mf * 16 + g * 4;
                        #pragma unroll
                        for (int r = 0; r < 4; ++r)
                            Lc[(rb + r) * 136 + col] = f2bf(acc[mf][nf][r] * sc);
                    }
            } else {
                #pragma unroll
                for (int mf = 0; mf < 8; ++mf)
                    #pragma unroll
                    for (int nf = 0; nf < 4; ++nf) {
                        const int col = (wn & 1) * 64 + nf * 16 + m;
                        const int rb  = wr * 128 + mf * 16 + g * 4;
                        ushort4 pk;
                        pk.x = f2bf(acc[mf][nf][0]); pk.y = f2bf(acc[mf][nf][1]);
                        pk.z = f2bf(acc[mf][nf][2]); pk.w = f2bf(acc[mf][nf][3]);
                        *(ushort4*)&Lc[col * 264 + rb] = pk;
                    }
            }
        }
        __syncthreads();
        if (!vmode) {
            #pragma unroll
            for (int it = 0; it < 8; ++it) {
                const int c   = tid + it * 512;
                const int row = c >> 4;
                const int c8  = (c & 15) * 8;
                const int n   = nbase + c8;
                const int which = (n >= 576);
                const int nn  = n - which * 576;
                const int h   = nn / 48, d = nn - h * 48;
                ushort_t* dst = outb + (size_t)which * per
                    + ((size_t)(b * Hn + h) * Tn + t0 + row) * Dn + d;
                *(ushort8_t*)dst = *(const ushort8_t*)&Lc[row * 136 + c8];
            }
        } else {
            #pragma unroll
            for (int it = 0; it < 8; ++it) {
                const int c   = tid + it * 512;
                const int col = c >> 5;
                const int rc  = (c & 31) * 8;
                const int n   = nbase + col;
                if (n < 1728) {
                    const int dd = n - 1152;
                    const int h  = dd / 48, d = dd - h * 48;
                    ushort_t* dst = outb + 2 * per
                        + ((size_t)(b * Hn + h) * Dn + d) * Tn + t0 + rc;
                    *(ushort8_t*)dst = *(const ushort8_t*)&Lc[col * 264 + rc];
                }
            }
        }
        __syncthreads();
    }
}

// ---------------------------------------------------------------------------
// proj GEMM: out = A[M,576] @ W[N,576]^T, fp32 out.  4-buffer / 3-ahead
// counted-vmcnt pipeline (round-10 config, best measured total).
// ---------------------------------------------------------------------------
template<int MODE, int MTILE>
__global__ __launch_bounds__(256)
void gemm_mfma(const ushort_t* __restrict__ A, const ushort_t* __restrict__ W,
               ushort_t* __restrict__ outb, float* __restrict__ outf)
{
    constexpr int SA   = MTILE / 16;
    constexpr int NSEG = SA + 4;
    constexpr int PW   = NSEG / 4;
    constexpr int MF   = MTILE / 64;
    constexpr int NB   = 9;
    constexpr int NST  = Cn / 32;
    constexpr int AH   = 3;
    constexpr int NBUF = 4;
    __shared__ __align__(16) ushort_t Ls[NBUF][NSEG][512];

    const int tid  = threadIdx.x;
    const int wave = tid >> 6;
    const int lane = tid & 63;
    const int m    = lane & 15;
    const int g    = lane >> 4;
    const int bid  = blockIdx.x;
    const int xcd  = bid & 7;
    const int slot = bid >> 3;
    const int n0   = (slot % NB) * 64;
    const int m0   = (xcd + 8 * (slot / NB)) * MTILE;

    floatx4 acc[MF][4];
    #pragma unroll
    for (int i = 0; i < MF; ++i)
        #pragma unroll
        for (int j = 0; j < 4; ++j)
            acc[i][j] = (floatx4){0.f, 0.f, 0.f, 0.f};

    const char* gp[PW];
    int         si[PW];
    #pragma unroll
    for (int i = 0; i < PW; ++i) {
        int s = wave + i * 4;
        si[i] = s;
        gp[i] = (s < SA)
            ? (const char*)(A + (size_t)(m0 + s * 16 + m) * Cn + g * 8)
            : (const char*)(W + (size_t)(n0 + (s - SA) * 16 + m) * Cn + g * 8);
    }

    #pragma unroll
    for (int s = 0; s < AH; ++s)
        #pragma unroll
        for (int i = 0; i < PW; ++i) { gload16(&Ls[s][si[i]][0], gp[i]); gp[i] += 64; }
    wait_vm_lg<(AH - 1) * PW>();
    __builtin_amdgcn_s_barrier();

    for (int j = 0; j < NST; ++j) {
        if (j + AH < NST) {
            #pragma unroll
            for (int i = 0; i < PW; ++i) {
                gload16(&Ls[(j + AH) & (NBUF - 1)][si[i]][0], gp[i]);
                gp[i] += 64;
            }
        }
        const int buf = j & (NBUF - 1);
        short8 bf4[4];
        #pragma unroll
        for (int jj = 0; jj < 4; ++jj)
            bf4[jj] = *(const short8*)&Ls[buf][SA + jj][lane * 8];
        #pragma unroll
        for (int i = 0; i < MF; ++i) {
            short8 afr = *(const short8*)&Ls[buf][wave * MF + i][lane * 8];
            #pragma unroll
            for (int jj = 0; jj < 4; ++jj)
                acc[i][jj] = __builtin_amdgcn_mfma_f32_16x16x32_bf16(afr, bf4[jj], acc[i][jj], 0, 0, 0);
        }
        if (j < NST - AH)        wait_vm_lg<(AH - 1) * PW>();
        else if (j == NST - AH)  wait_vm_lg<(AH - 2) * PW>();
        else                     wait_vm_lg<0>();
        __builtin_amdgcn_s_barrier();
    }

    #pragma unroll
    for (int i = 0; i < MF; ++i) {
        #pragma unroll
        for (int r = 0; r < 4; ++r) {
            int mrow = m0 + wave * (MTILE / 4) + i * 16 + g * 4 + r;
            #pragma unroll
            for (int j = 0; j < 4; ++j)
                outf[(size_t)mrow * Cn + n0 + j * 16 + m] = acc[i][j][r];
        }
    }
}

// ---------------------------------------------------------------------------
// ROUND-13 flash attention: KVBLK 64 -> 128.  r2 counters (Mfma 18%, VALU
// 36%, 46% issue-dead) point at the per-tile serial chain + __syncthreads
// (vmcnt-drain) paid once per 64 K-rows, up to 32x per block.  Same total
// MFMA/VALU work, HALF the barriers: one sync per 128 K-rows, 28 MFMAs per
// sync.  P^T for 128 j reuses the 2 dead-Q strips twice (wave-private,
// in-order LDS: lgkmcnt(0) between halves, no barrier).  Mask branch is now
// block-uniform (only the last tile straddles the diagonal).  exp2 written
// in place over s[] to hold VGPR <= 128 (launch_bounds 512,4).
// LDS 72KB -> 2 blocks/CU.  Grid 768 = 16 qtiles x 48 bh, big/small paired.
// ---------------------------------------------------------------------------
__global__ __launch_bounds__(512, 4)
void attn_mfma(const ushort_t* __restrict__ Q, const ushort_t* __restrict__ K,
               const ushort_t* __restrict__ V, ushort_t* __restrict__ Y,
               const ushort_t* __restrict__ zb)
{
    __shared__ __align__(16) ushort_t QPs[16][512];    // Q tile, then reused as P^T
    __shared__ __align__(16) ushort_t Ks[2][16][512];  // [buf][(jrow16 t)*2 + khalf]
    __shared__ __align__(16) ushort_t Vs[2][12][512];  // [buf][(dtile t)*4 + colq]

    const int id   = blockIdx.x;
    const int kk   = id / 48;
    const int bh   = id - kk * 48;
    const int QT   = (kk & 1) ? (kk >> 1) : (15 - (kk >> 1));   // interleave big/small
    const int tid  = threadIdx.x;
    const int wave = tid >> 6;       // 0..7
    const int lane = tid & 63;
    const int m    = lane & 15;
    const int g    = lane >> 4;
    const int q0   = QT * 128;
    const int nkt  = QT + 1;         // 128-row K tiles to process

    const ushort_t* Qp = Q + (size_t)bh * Tn * Dn;
    const ushort_t* Kp = K + (size_t)bh * Tn * Dn;
    const ushort_t* Vp = V + (size_t)bh * Dn * Tn;     // [48][T]

    // ---- Q staging: wave w stages strips 2w,2w+1 (rows q0+w*16+m) ----
    {
        const char* qrp = (const char*)(Qp + (size_t)(q0 + wave * 16 + m) * Dn);
        gload16(&QPs[wave * 2 + 0][0], qrp + g * 16);
        gload16(&QPs[wave * 2 + 1][0], (g < 2) ? (qrp + 64 + g * 16) : (const char*)zb);
    }

    // ---- K staging: wave w owns segs w and w+8.  Seg s: rows (s>>1)*16 + m,
    //      k-bytes (s&1)*64 + g*16 (g>=2 of odd segs -> zero pad). ----
    const bool  kpad  = ((wave & 1) == 1) && (g >= 2);
    const char* kptrA = kpad ? (const char*)zb
        : (const char*)(Kp + (size_t)((wave >> 1) * 16 + m) * Dn) + (wave & 1) * 64 + g * 16;
    const char* kptrB = kpad ? (const char*)zb
        : kptrA + 64 * Dn * 2;                         // rows +64
    const int   kadv  = kpad ? 0 : 128 * Dn * 2;       // 128 K-rows per tile

    // ---- V staging: wave w<6 owns segs 2w (t=w>>1, kc=2*(w&1)) and 2w+1.
    //      Seg v=(t*4+kc): V^T rows t*16+m, col-bytes kc*64 + g*16. ----
    const char* vptr0 = (const char*)(Vp + (size_t)((wave >> 1) * 16 + m) * Tn)
                        + (2 * (wave & 1)) * 64 + g * 16;
    const char* vptr1 = vptr0 + 64;
    const int   vadv  = 128 * 2;                       // 128 V^T-cols per tile

    // prologue: stage K/V tile 0 into buf 0
    gload16(&Ks[0][wave][0],     kptrA); kptrA += kadv;
    gload16(&Ks[0][wave + 8][0], kptrB); kptrB += kadv;
    if (wave < 6) {
        gload16(&Vs[0][2 * wave + 0][0], vptr0); vptr0 += vadv;
        gload16(&Vs[0][2 * wave + 1][0], vptr1); vptr1 += vadv;
    }
    __syncthreads();   // drains vmcnt -> Q + tile0 ready

    // loop-invariant B-fragments (Q); QPs strip (wave-private) then dead -> P^T
    short8 bq[2];
    bq[0] = *(const short8*)&QPs[wave * 2 + 0][lane * 8];
    bq[1] = *(const short8*)&QPs[wave * 2 + 1][lane * 8];

    floatx4 acc[3];
    #pragma unroll
    for (int t = 0; t < 3; ++t) acc[t] = (floatx4){0.f, 0.f, 0.f, 0.f};
    float l_tot = 0.f;
    const int qrow  = q0 + wave * 16 + m;    // this lane's global query row
    const int qwmax = q0 + wave * 16 + 15;   // wave's max query row

    for (int jt = 0; jt < nkt; ++jt) {
        const int cur = jt & 1;
        const int j0  = jt * 128;
        // issue async staging for tile jt+1 (overlaps this tile's compute)
        if (jt + 1 < nkt) {
            gload16(&Ks[cur ^ 1][wave][0],     kptrA); kptrA += kadv;
            gload16(&Ks[cur ^ 1][wave + 8][0], kptrB); kptrB += kadv;
            if (wave < 6) {
                gload16(&Vs[cur ^ 1][2 * wave + 0][0], vptr0); vptr0 += vadv;
                gload16(&Vs[cur ^ 1][2 * wave + 1][0], vptr1); vptr1 += vadv;
            }
        }

        if (j0 <= qwmax) {   // wave-uniform: at least one unmasked element
            // ---- S^T = K Q^T : D[m=j (8 tiles)][n=q] ----
            floatx4 s[8];
            #pragma unroll
            for (int t = 0; t < 8; ++t) {
                s[t] = (floatx4){0.f, 0.f, 0.f, 0.f};
                #pragma unroll
                for (int kc = 0; kc < 2; ++kc) {
                    short8 ak = *(const short8*)&Ks[cur][t * 2 + kc][lane * 8];
                    s[t] = __builtin_amdgcn_mfma_f32_16x16x32_bf16(ak, bq[kc], s[t], 0, 0, 0);
                }
            }

            // ---- mask (last tile only: block-uniform) + exp2 in place ----
            float lsum = 0.f;
            if (jt == nkt - 1) {
                #pragma unroll
                for (int t = 0; t < 8; ++t)
                    #pragma unroll
                    for (int r = 0; r < 4; ++r) {
                        int j = j0 + t * 16 + g * 4 + r;
                        float v = (j <= qrow) ? s[t][r] : -1e30f;
                        float e = __builtin_amdgcn_exp2f(v);
                        s[t][r] = e; lsum += e;
                    }
            } else {
                #pragma unroll
                for (int t = 0; t < 8; ++t)
                    #pragma unroll
                    for (int r = 0; r < 4; ++r) {
                        float e = __builtin_amdgcn_exp2f(s[t][r]);
                        s[t][r] = e; lsum += e;
                    }
            }
            lsum += __shfl_xor(lsum, 16);
            lsum += __shfl_xor(lsum, 32);
            l_tot += lsum;

            // ---- PV in two 64-j halves, reusing the 2 dead-Q strips ----
            #pragma unroll
            for (int hh = 0; hh < 2; ++hh) {
                // store P^T half hh (t4 = local 16-j tile) in B-frag order
                #pragma unroll
                for (int t4 = 0; t4 < 4; ++t4) {
                    const int t = hh * 4 + t4;
                    uint2 w2;
                    w2.x = pack_trunc(s[t][0], s[t][1]);
                    w2.y = pack_trunc(s[t][2], s[t][3]);
                    *(uint2*)&QPs[wave * 2 + (t4 >> 1)]
                                 [(2 * (t4 & 1) + (g >> 1)) * 128 + m * 8 + (g & 1) * 4] = w2;
                }
                // wave-private strip: drain own LDS writes (in-order DS queue
                // also guarantees prior bp reads completed first)
                asm volatile("s_waitcnt lgkmcnt(0)" ::: "memory");

                // O^T += V^T[:, half hh] P^T[half hh]
                #pragma unroll
                for (int kc2 = 0; kc2 < 2; ++kc2) {
                    const int kcq = hh * 2 + kc2;      // global col-quarter
                    short8 bp = *(const short8*)&QPs[wave * 2 + kc2][lane * 8];
                    #pragma unroll
                    for (int t = 0; t < 3; ++t) {
                        short8 av = *(const short8*)&Vs[cur][t * 4 + kcq][lane * 8];
                        acc[t] = __builtin_amdgcn_mfma_f32_16x16x32_bf16(av, bp, acc[t], 0, 0, 0);
                    }
                }
            }
        }

        __syncthreads();   // next tile staged (vmcnt drain) + cur-buf reads done
    }

    // ---- epilogue: lane holds O^T[d = t*16+g*4+r][qrow]; normalize, store ----
    const float inv = 1.0f / l_tot;
    const int b = bh / Hn;
    const int h = bh - b * Hn;
    ushort_t* yp = Y + ((size_t)(b * Tn + qrow)) * Cn + h * Dn;
    #pragma unroll
    for (int t = 0; t < 3; ++t) {
        ushort4 o;
        o.x = f2bf(acc[t][0] * inv);
        o.y = f2bf(acc[t][1] * inv);
        o.z = f2bf(acc[t][2] * inv);
        o.w = f2bf(acc[t][3] * inv);
        *(ushort4*)&yp[t * 16 + g * 4] = o;
    }
}

// ---------------------------------------------------------------------------
extern "C" void kernel_launch(void* const* d_in, const int* in_sizes, int n_in,
                              void* d_out, int out_size, void* d_ws, size_t ws_size,
                              hipStream_t stream)
{
    const float* x      = (const float*)d_in[0];   // [B,T,C]
    const float* w_qkv  = (const float*)d_in[1];   // [3C,C]
    const float* w_proj = (const float*)d_in[2];   // [C,C]
    float* out = (float*)d_out;                    // [B,T,C] fp32

    const size_t per = (size_t)Bn * Hn * Tn * Dn;  // 4,718,592

    ushort_t* xb  = (ushort_t*)d_ws;               // 8192*576
    ushort_t* wqb = xb  + (size_t)Mn * Cn;         // 1728*576 (+64 pad rows read into wpb)
    ushort_t* wpb = wqb + (size_t)3 * Cn * Cn;     // 576*576
    ushort_t* qkv = wpb + (size_t)Cn * Cn;         // 3*per (q | k | v^T)
    ushort_t* yb  = qkv + 3 * per;                 // 8192*576
    ushort_t* zb  = yb  + (size_t)Mn * Cn;         // 256 B of zeros (Q/K pad source)

    // fused casts (fp32 -> bf16) + zb zeroing
    const int na4 = Mn * Cn / 4, nb4 = 3 * Cn * Cn / 4, nc4 = Cn * Cn / 4;
    cast3<<<dim3((na4 + nb4 + nc4 + 255) / 256), dim3(256), 0, stream>>>(
        x, xb, na4, w_qkv, wqb, nb4, w_proj, wpb, nc4, zb);

    // QKV GEMM (M=8192, N=1792 padded): 224 blocks, 8-phase schedule
    gemm_qkv<<<dim3(224), dim3(512), 0, stream>>>(xb, wqb, qkv);

    // causal attention (ALiBi bias is exactly zero on the unmasked region)
    attn_mfma<<<dim3((Tn / 128) * Bn * Hn), dim3(512), 0, stream>>>(
        qkv, qkv + per, qkv + 2 * per, yb, zb);

    // output projection (M=8192, N=576) -> fp32: 576 blocks, XCD-swizzled
    gemm_mfma<1, 128><<<dim3((Mn / 128) * 9), dim3(256), 0, stream>>>(yb, wpb, nullptr, out);
}